// Round 8
// baseline (3859.462 us; speedup 1.0000x reference)
//
#include <hip/hip_runtime.h>
#include <hip/hip_bf16.h>
#include <math.h>

using bf16 = __hip_bfloat16;

constexpr int CB = 4, CN = 1024, CD = 256, CH = 4, CFF = 2048;
constexpr int CNL = 2, CGL = 3, CK = 5, CBN = CB * CN;

// ---------------------------------------------------------------------------
// Generic tiled GEMM: C[m,n] = scale * sum_k A[m,k] * (TRANSB ? B[n,k] : B[k,n])
//                     (+ bias[n]) (+= old C if ACCUM) (relu if RELU)
// Tile 64x64, K-step 16, 256 threads, 4x4 accum per thread. All f32.
// ---------------------------------------------------------------------------
template<bool TRANSB, bool RELU, bool ACCUM>
__global__ __launch_bounds__(256) void gemm_k(
    const float* __restrict__ A, int lda, long sAb, long sAz,
    const float* __restrict__ Bm, int ldb, long sBb, long sBz,
    float* __restrict__ C, int ldc, long sCb, long sCz,
    const float* __restrict__ bias, float scale, int K, int zdiv)
{
  __shared__ float As[16][64];
  __shared__ float Bs[16][64];
  const int t = threadIdx.x;
  const int z = blockIdx.z;
  const int zb = z / zdiv, zh = z - zb * zdiv;
  const float* Ap = A + (long)zb * sAb + (long)zh * sAz;
  const float* Bp = Bm + (long)zb * sBb + (long)zh * sBz;
  float* Cp = C + (long)zb * sCb + (long)zh * sCz;
  const int m0 = blockIdx.y * 64, n0 = blockIdx.x * 64;
  const int lr = t >> 2;           // 0..63 tile row
  const int lk = (t & 3) << 2;     // k quad
  const int mr = (t >> 4) << 2;    // this thread's 4 output rows
  const int nc = (t & 15) << 2;    // this thread's 4 output cols
  float acc[4][4] = {};
  for (int k0 = 0; k0 < K; k0 += 16) {
    float4 av = *(const float4*)&Ap[(long)(m0 + lr) * lda + k0 + lk];
    As[lk + 0][lr] = av.x; As[lk + 1][lr] = av.y;
    As[lk + 2][lr] = av.z; As[lk + 3][lr] = av.w;
    if (TRANSB) {
      float4 bv = *(const float4*)&Bp[(long)(n0 + lr) * ldb + k0 + lk];
      Bs[lk + 0][lr] = bv.x; Bs[lk + 1][lr] = bv.y;
      Bs[lk + 2][lr] = bv.z; Bs[lk + 3][lr] = bv.w;
    } else {
      const int bk = t >> 4, bn2 = (t & 15) << 2;
      float4 bv = *(const float4*)&Bp[(long)(k0 + bk) * ldb + n0 + bn2];
      Bs[bk][bn2 + 0] = bv.x; Bs[bk][bn2 + 1] = bv.y;
      Bs[bk][bn2 + 2] = bv.z; Bs[bk][bn2 + 3] = bv.w;
    }
    __syncthreads();
#pragma unroll
    for (int k = 0; k < 16; ++k) {
      float4 a = *(const float4*)&As[k][mr];
      float4 b = *(const float4*)&Bs[k][nc];
      acc[0][0] += a.x * b.x; acc[0][1] += a.x * b.y; acc[0][2] += a.x * b.z; acc[0][3] += a.x * b.w;
      acc[1][0] += a.y * b.x; acc[1][1] += a.y * b.y; acc[1][2] += a.y * b.z; acc[1][3] += a.y * b.w;
      acc[2][0] += a.z * b.x; acc[2][1] += a.z * b.y; acc[2][2] += a.z * b.z; acc[2][3] += a.z * b.w;
      acc[3][0] += a.w * b.x; acc[3][1] += a.w * b.y; acc[3][2] += a.w * b.z; acc[3][3] += a.w * b.w;
    }
    __syncthreads();
  }
#pragma unroll
  for (int i = 0; i < 4; ++i) {
    float* crow = Cp + (long)(m0 + mr + i) * ldc + n0 + nc;
#pragma unroll
    for (int j = 0; j < 4; ++j) {
      float v = acc[i][j] * scale;
      if (bias) v += bias[n0 + nc + j];
      if (ACCUM) v += crow[j];
      if (RELU) v = fmaxf(v, 0.f);
      crow[j] = v;
    }
  }
}

// ---------------------------------------------------------------------------
// Fused flash-style attention for one (q-tile of 64, b*4+h). LDS 48 KiB.
// QKV: (4096 x 768) f32, q|k|v at col 0|256|512, head h at +h*64.
// O:   (4096 x 256) f32, head h at col h*64.  (validated vs naive impl, R6)
// ---------------------------------------------------------------------------
__global__ __launch_bounds__(256) void attn_k(const float* __restrict__ QKV,
                                              float* __restrict__ O)
{
  const int t = threadIdx.x;
  const int q0 = blockIdx.x * 64;
  const int b = blockIdx.y >> 2, h = blockIdx.y & 3;
  const float* base = QKV + (long)b * 786432;
  const int hc = h * 64;
  __shared__ float Qs[64][64];   // [d][m]
  __shared__ float KPs[64][64];  // S-phase: [d][n] = K^T;  PV-phase: [k][m] = P^T
  __shared__ float Vs[64][64];   // [k][d]
  const int ldr = t >> 2;
  const int ldc0 = (t & 3) * 16;
  {
    const float* qrow = base + (long)(q0 + ldr) * 768 + hc;
#pragma unroll
    for (int j = 0; j < 16; j += 4) {
      float4 v = *(const float4*)(qrow + ldc0 + j);
      Qs[ldc0 + j + 0][ldr] = v.x; Qs[ldc0 + j + 1][ldr] = v.y;
      Qs[ldc0 + j + 2][ldr] = v.z; Qs[ldc0 + j + 3][ldr] = v.w;
    }
  }
  const int mr = (t >> 4) << 2;
  const int nc = (t & 15) << 2;
  float mrow[4] = {-INFINITY, -INFINITY, -INFINITY, -INFINITY};
  float lrow[4] = {0.f, 0.f, 0.f, 0.f};
  float acc[4][4] = {};
  for (int kt = 0; kt < 16; ++kt) {
    __syncthreads();
    {
      const float* krow = base + (long)(kt * 64 + ldr) * 768 + 256 + hc;
      const float* vrow = base + (long)(kt * 64 + ldr) * 768 + 512 + hc;
#pragma unroll
      for (int j = 0; j < 16; j += 4) {
        float4 kv = *(const float4*)(krow + ldc0 + j);
        KPs[ldc0 + j + 0][ldr] = kv.x; KPs[ldc0 + j + 1][ldr] = kv.y;
        KPs[ldc0 + j + 2][ldr] = kv.z; KPs[ldc0 + j + 3][ldr] = kv.w;
        float4 vv = *(const float4*)(vrow + ldc0 + j);
        *(float4*)&Vs[ldr][ldc0 + j] = vv;
      }
    }
    __syncthreads();
    float s[4][4] = {};
#pragma unroll 8
    for (int d = 0; d < 64; ++d) {
      float4 a = *(const float4*)&Qs[d][mr];
      float4 bv = *(const float4*)&KPs[d][nc];
      s[0][0] += a.x * bv.x; s[0][1] += a.x * bv.y; s[0][2] += a.x * bv.z; s[0][3] += a.x * bv.w;
      s[1][0] += a.y * bv.x; s[1][1] += a.y * bv.y; s[1][2] += a.y * bv.z; s[1][3] += a.y * bv.w;
      s[2][0] += a.z * bv.x; s[2][1] += a.z * bv.y; s[2][2] += a.z * bv.z; s[2][3] += a.z * bv.w;
      s[3][0] += a.w * bv.x; s[3][1] += a.w * bv.y; s[3][2] += a.w * bv.z; s[3][3] += a.w * bv.w;
    }
#pragma unroll
    for (int i = 0; i < 4; ++i) {
#pragma unroll
      for (int j = 0; j < 4; ++j) s[i][j] *= 0.125f;
      float rm = fmaxf(fmaxf(s[i][0], s[i][1]), fmaxf(s[i][2], s[i][3]));
      rm = fmaxf(rm, __shfl_xor(rm, 1));
      rm = fmaxf(rm, __shfl_xor(rm, 2));
      rm = fmaxf(rm, __shfl_xor(rm, 4));
      rm = fmaxf(rm, __shfl_xor(rm, 8));
      float mn = fmaxf(mrow[i], rm);
      float corr = expf(mrow[i] - mn);
      float rs = 0.f;
#pragma unroll
      for (int j = 0; j < 4; ++j) {
        float p = expf(s[i][j] - mn);
        s[i][j] = p; rs += p;
      }
      rs += __shfl_xor(rs, 1);
      rs += __shfl_xor(rs, 2);
      rs += __shfl_xor(rs, 4);
      rs += __shfl_xor(rs, 8);
      lrow[i] = lrow[i] * corr + rs;
      mrow[i] = mn;
#pragma unroll
      for (int j = 0; j < 4; ++j) acc[i][j] *= corr;
    }
    __syncthreads();
#pragma unroll
    for (int i = 0; i < 4; ++i)
#pragma unroll
      for (int j = 0; j < 4; ++j)
        KPs[nc + j][mr + i] = s[i][j];
    __syncthreads();
#pragma unroll 8
    for (int k = 0; k < 64; ++k) {
      float4 p = *(const float4*)&KPs[k][mr];
      float4 v = *(const float4*)&Vs[k][nc];
      acc[0][0] += p.x * v.x; acc[0][1] += p.x * v.y; acc[0][2] += p.x * v.z; acc[0][3] += p.x * v.w;
      acc[1][0] += p.y * v.x; acc[1][1] += p.y * v.y; acc[1][2] += p.y * v.z; acc[1][3] += p.y * v.w;
      acc[2][0] += p.z * v.x; acc[2][1] += p.z * v.y; acc[2][2] += p.z * v.z; acc[2][3] += p.z * v.w;
      acc[3][0] += p.w * v.x; acc[3][1] += p.w * v.y; acc[3][2] += p.w * v.z; acc[3][3] += p.w * v.w;
    }
  }
#pragma unroll
  for (int i = 0; i < 4; ++i) {
    float inv = 1.f / lrow[i];
    float* orow = O + (long)(b * 1024 + q0 + mr + i) * 256 + hc + nc;
    orow[0] = acc[i][0] * inv; orow[1] = acc[i][1] * inv;
    orow[2] = acc[i][2] * inv; orow[3] = acc[i][3] * inv;
  }
}

// ---------------------------------------------------------------------------
// out = LN(x + y) * g + b   (rows of 256, one block per row) — f32 out
// ---------------------------------------------------------------------------
__global__ __launch_bounds__(256) void resln_k(
    const float* __restrict__ x, const float* __restrict__ y,
    const float* __restrict__ g, const float* __restrict__ be, float* __restrict__ out)
{
  const long row = blockIdx.x;
  const int t = threadIdx.x;
  float v = x[row * 256 + t] + y[row * 256 + t];
  float s = v;
#pragma unroll
  for (int o = 32; o > 0; o >>= 1) s += __shfl_xor(s, o);
  __shared__ float w1r[4];
  __shared__ float w2r[4];
  if ((t & 63) == 0) w1r[t >> 6] = s;
  __syncthreads();
  float mean = (w1r[0] + w1r[1] + w1r[2] + w1r[3]) * (1.f / 256.f);
  float d = v - mean;
  float q = d * d;
#pragma unroll
  for (int o = 32; o > 0; o >>= 1) q += __shfl_xor(q, o);
  if ((t & 63) == 0) w2r[t >> 6] = q;
  __syncthreads();
  float var = (w2r[0] + w2r[1] + w2r[2] + w2r[3]) * (1.f / 256.f);
  out[row * 256 + t] = d * (1.f / sqrtf(var + 1e-5f)) * g[t] + be[t];
}

// ---------------------------------------------------------------------------
// Fused beat encoder (one block per (b,n)); writes e and masked em.
// ---------------------------------------------------------------------------
__global__ __launch_bounds__(256) void encoder_k(
    const float* __restrict__ beats, const float* __restrict__ rr,
    const float* __restrict__ c1w, const float* __restrict__ c1b,
    const float* __restrict__ c2w, const float* __restrict__ c2b,
    const float* __restrict__ fcw, const float* __restrict__ fcb,
    const float* __restrict__ mtok, const int* __restrict__ nmask,
    const float* __restrict__ vmask,
    float* __restrict__ e, float* __restrict__ em)
{
  const int bn = blockIdx.x;
  const int t = threadIdx.x;
  __shared__ float xin[256];
  __shared__ float o1[32][128];
  __shared__ float w2s[64 * 32 * 5];
  __shared__ float w1s[32 * 5];
  __shared__ float b1s[32];
  __shared__ float b2s[64];
  __shared__ float pooled[66];
  xin[t] = beats[(long)bn * 256 + t];
  for (int i = t; i < 64 * 32 * 5; i += 256) w2s[i] = c2w[i];
  if (t < 160) w1s[t] = c1w[t];
  if (t < 32) b1s[t] = c1b[t];
  if (t < 64) b2s[t] = c2b[t];
  if (t < 66) pooled[t] = 0.f;
  __syncthreads();
  for (int r = 0; r < 16; ++r) {
    int idx = t + 256 * r;
    int c = idx >> 7, l = idx & 127;
    float acc = b1s[c];
    int base = 2 * l - 2;
#pragma unroll
    for (int u = 0; u < 5; ++u) {
      int ii = base + u;
      if (ii >= 0 && ii < 256) acc += xin[ii] * w1s[c * 5 + u];
    }
    o1[c][l] = fmaxf(acc, 0.f);
  }
  __syncthreads();
  for (int r = 0; r < 16; ++r) {
    int idx = t + 256 * r;
    int c = idx >> 6, l = idx & 63;
    float acc = b2s[c];
    int base = 2 * l - 2;
    for (int ci = 0; ci < 32; ++ci) {
      const float* wrow = &w2s[(c * 32 + ci) * 5];
#pragma unroll
      for (int u = 0; u < 5; ++u) {
        int ii = base + u;
        if (ii >= 0 && ii < 128) acc += o1[ci][ii] * wrow[u];
      }
    }
    acc = fmaxf(acc, 0.f);
#pragma unroll
    for (int o = 32; o > 0; o >>= 1) acc += __shfl_xor(acc, o);
    if ((t & 63) == 0) pooled[c] += acc * (1.f / 64.f);  // c = wave + 4r: disjoint
  }
  if (t == 64) pooled[64] = rr[(long)bn * 2 + 0];
  if (t == 65) pooled[65] = rr[(long)bn * 2 + 1];
  __syncthreads();
  float acc = fcb[t];
  for (int k = 0; k < 66; ++k) acc += pooled[k] * fcw[t * 66 + k];
  e[(long)bn * 256 + t] = acc;
  float mv = nmask[bn] ? mtok[t] : acc;
  em[(long)bn * 256 + t] = mv * vmask[bn];
}

// ---------------------------------------------------------------------------
// Top-5 per sim row (ties -> lower index), union band {i-1,i+1}. One batch.
// ---------------------------------------------------------------------------
__global__ __launch_bounds__(256) void topk_k(const float* __restrict__ sim, int b,
    int* __restrict__ nbr, float* __restrict__ deg)
{
  const int i = blockIdx.x;
  const float* row = sim + (long)i * CN;
  const int t = threadIdx.x;
  float v[4]; int id[4];
  float4 rv = ((const float4*)row)[t];
  v[0] = rv.x; v[1] = rv.y; v[2] = rv.z; v[3] = rv.w;
#pragma unroll
  for (int j = 0; j < 4; ++j) id[j] = t * 4 + j;
  __shared__ float vr[256];
  __shared__ int ir[256];
  __shared__ int chosen[CK];
  for (int kk = 0; kk < CK; ++kk) {
    float bv = v[0]; int bi = id[0];
#pragma unroll
    for (int j = 1; j < 4; ++j)
      if (v[j] > bv || (v[j] == bv && id[j] < bi)) { bv = v[j]; bi = id[j]; }
    vr[t] = bv; ir[t] = bi;
    __syncthreads();
    for (int s2 = 128; s2 > 0; s2 >>= 1) {
      if (t < s2) {
        float ov = vr[t + s2]; int oi = ir[t + s2];
        if (ov > vr[t] || (ov == vr[t] && oi < ir[t])) { vr[t] = ov; ir[t] = oi; }
      }
      __syncthreads();
    }
    if (t == 0) chosen[kk] = ir[0];
    __syncthreads();
    int c = chosen[kk];
#pragma unroll
    for (int j = 0; j < 4; ++j) if (id[j] == c) v[j] = -INFINITY;
  }
  if (t == 0) {
    int list[CK + 2]; int cnt = 0;
    for (int kk = 0; kk < CK; ++kk) list[cnt++] = chosen[kk];
    if (i > 0) {
      bool found = false;
      for (int j = 0; j < CK; ++j) if (chosen[j] == i - 1) found = true;
      if (!found) list[cnt++] = i - 1;
    }
    if (i < CN - 1) {
      bool found = false;
      for (int j = 0; j < CK; ++j) if (chosen[j] == i + 1) found = true;
      if (!found) list[cnt++] = i + 1;
    }
    deg[(long)b * CN + i] = (float)cnt;
    for (int j = 0; j < 8; ++j)
      nbr[((long)b * CN + i) * 8 + j] = (j < cnt) ? list[j] : -1;
  }
}

// ---------------------------------------------------------------------------
// Sparse GNN aggregate: agg[i,:] = sum_{j in nbr(i)} x[j,:] / (deg + 1e-6)
// ---------------------------------------------------------------------------
__global__ __launch_bounds__(256) void agg_k(const float* __restrict__ x,
    const int* __restrict__ nbr, const float* __restrict__ deg, float* __restrict__ agg)
{
  const long row = blockIdx.x;
  const int t = threadIdx.x;
  const long bbase = (row >> 10) << 10;
  const int* nb = &nbr[row * 8];
  float s = 0.f;
  for (int j = 0; j < 8; ++j) {
    int n2 = nb[j];
    if (n2 >= 0) s += x[(bbase + n2) * 256 + t];
  }
  agg[row * 256 + t] = s / (deg[row] + 1e-6f);
}

// ---------------------------------------------------------------------------
// Bool-mask upload-layout detection + build.
// ---------------------------------------------------------------------------
__global__ void maskdetect_k(const unsigned char* __restrict__ p, int* __restrict__ flag) {
  int i = blockIdx.x * 256 + threadIdx.x;
  unsigned char c = p[i];
  int f = 0;
  if (c == 0x01) f |= 1;
  if (c == 0x3F || c == 0x80) f |= 2;
  if (c != 0 && (i & 3) == 1) f |= 4;
  if (c != 0 && ((i & 3) == 2 || (i & 3) == 3)) f |= 8;
  if (f) atomicOr(flag, f);
}
__global__ void maskbuild_k(const void* __restrict__ nm, const void* __restrict__ vm,
                            const int* __restrict__ flag, int* __restrict__ outm,
                            float* __restrict__ outv) {
  int i = blockIdx.x * 256 + threadIdx.x;
  int f = *flag;
  int layout;                                // 0=i32, 1=i8, 2=bf16, 3=f32
  if (f & 2) layout = (f & 4) ? 2 : 3;
  else if (f & (4 | 8)) layout = 1;
  else layout = 0;
  bool m, vv;
  if (layout == 1)      { m = ((const unsigned char*)nm)[i] != 0;  vv = ((const unsigned char*)vm)[i] != 0; }
  else if (layout == 0) { m = ((const int*)nm)[i] != 0;            vv = ((const int*)vm)[i] != 0; }
  else if (layout == 2) { m = ((const unsigned short*)nm)[i] != 0; vv = ((const unsigned short*)vm)[i] != 0; }
  else                  { m = ((const unsigned int*)nm)[i] != 0;   vv = ((const unsigned int*)vm)[i] != 0; }
  outm[i] = m ? 1 : 0;
  outv[i] = vv ? 1.f : 0.f;
}

// ---------------------------------------------------------------------------
// Host-side: post-norm transformer stack; final LN writes f32 to xfinal.
// ---------------------------------------------------------------------------
static void run_temporal(const float* x0, float* bufX, float* xfinal,
    const float* qkv_w, const float* qkv_b, const float* out_w, const float* out_b,
    const float* ln1g, const float* ln1b, const float* w1, const float* b1,
    const float* w2, const float* b2, const float* ln2g, const float* ln2b,
    float* F_QKV, float* F_H, float* F_O, float* F_T, hipStream_t stream)
{
  for (int l = 0; l < CNL; ++l) {
    const float* xs = (l == 0) ? x0 : bufX;
    // qkv = x @ qkv_w.T + qkv_b        (4096 x 768)
    gemm_k<true, false, false><<<dim3(12, 64, 1), 256, 0, stream>>>(
        xs, 256, 0, 0, qkv_w + (long)l * 768 * 256, 256, 0, 0,
        F_QKV, 768, 0, 0, qkv_b + l * 768, 1.f, 256, 1);
    // fused attention -> F_O
    attn_k<<<dim3(16, 16), 256, 0, stream>>>(F_QKV, F_O);
    // proj = O @ out_w.T + out_b
    gemm_k<true, false, false><<<dim3(4, 64, 1), 256, 0, stream>>>(
        F_O, 256, 0, 0, out_w + (long)l * 65536, 256, 0, 0,
        F_T, 256, 0, 0, out_b + l * 256, 1.f, 256, 1);
    // x = LN(x + proj)
    resln_k<<<CBN, 256, 0, stream>>>(xs, F_T, ln1g + l * 256, ln1b + l * 256, bufX);
    // FFN in 4 chunks of 1024 rows (h reuses the dead QKV region)
    for (int c = 0; c < 4; ++c) {
      const float* xc = bufX + (long)c * 262144;
      gemm_k<true, true, false><<<dim3(32, 16, 1), 256, 0, stream>>>(
          xc, 256, 0, 0, w1 + (long)l * 2048 * 256, 256, 0, 0,
          F_H, 2048, 0, 0, b1 + l * 2048, 1.f, 256, 1);
      gemm_k<true, false, false><<<dim3(4, 16, 1), 256, 0, stream>>>(
          F_H, 2048, 0, 0, w2 + (long)l * 2048 * 256, 2048, 0, 0,
          F_T + (long)c * 262144, 256, 0, 0, b2 + l * 256, 1.f, 2048, 1);
    }
    // x = LN(x + h2)
    float* dst = (l < CNL - 1) ? bufX : xfinal;
    resln_k<<<CBN, 256, 0, stream>>>(bufX, F_T, ln2g + l * 256, ln2b + l * 256, dst);
  }
}

extern "C" void kernel_launch(void* const* d_in, const int* in_sizes, int n_in,
                              void* d_out, int out_size, void* d_ws, size_t ws_size,
                              hipStream_t stream)
{
  (void)in_sizes; (void)n_in; (void)out_size; (void)ws_size;
  const float* beats = (const float*)d_in[0];
  const float* rr    = (const float*)d_in[1];
  const void*  nmask = d_in[2];
  const void*  vmask = d_in[3];
  const float* c1w  = (const float*)d_in[4];
  const float* c1b  = (const float*)d_in[5];
  const float* c2w  = (const float*)d_in[6];
  const float* c2b  = (const float*)d_in[7];
  const float* fcw  = (const float*)d_in[8];
  const float* fcb  = (const float*)d_in[9];
  const float* mtok = (const float*)d_in[10];
  const float* qkv_w = (const float*)d_in[11];
  const float* qkv_b = (const float*)d_in[12];
  const float* out_w = (const float*)d_in[13];
  const float* out_b = (const float*)d_in[14];
  const float* ln1g = (const float*)d_in[15];
  const float* ln1b = (const float*)d_in[16];
  const float* w1   = (const float*)d_in[17];
  const float* b1   = (const float*)d_in[18];
  const float* w2   = (const float*)d_in[19];
  const float* b2   = (const float*)d_in[20];
  const float* ln2g = (const float*)d_in[21];
  const float* ln2b = (const float*)d_in[22];
  const float* gsw  = (const float*)d_in[23];
  const float* gsb  = (const float*)d_in[24];
  const float* gnw  = (const float*)d_in[25];
  const float* gnb  = (const float*)d_in[26];
  const float* dcw  = (const float*)d_in[27];
  const float* dcb  = (const float*)d_in[28];
  float* out = (float*)d_out;   // *** f32 output: reference returns float32 ***

  // ---- workspace layout (~32.3 MB of f32) ----
  float* W = (float*)d_ws;
  const long M1 = 1048576;
  float* F_X   = W + 0 * M1;    // current x
  float* F_E   = W + 1 * M1;    // encoder out / GNN ping-pong
  float* F_EM  = W + 2 * M1;    // masked encoder out / GNN agg
  float* F_QKV = W + 3 * M1;    // 4096x768 (3M); aliased: FFN h (2M), sim (1M)
  float* F_O   = W + 6 * M1;    // attn out
  float* F_T   = W + 7 * M1;    // proj / ffn2 tmp
  float* MISC  = W + 8 * M1;
  float* F_DEG = MISC;                    // 4096
  float* F_VAL = MISC + 4096;             // 4096
  int*   I_MASK = (int*)(MISC + 8192);    // 4096
  int*   I_NBR  = I_MASK + 4096;          // 4096*8
  int*   I_FLAG = I_NBR + 4096 * 8;       // 1
  float* F_H   = F_QKV;
  float* F_SIM = F_QKV;
  float* F_G2  = F_E;
  float* F_AGG = F_EM;

  // --- masks (layout-detected) ---
  hipMemsetAsync(I_FLAG, 0, 4, stream);
  maskdetect_k<<<16, 256, 0, stream>>>((const unsigned char*)nmask, I_FLAG);
  maskbuild_k<<<16, 256, 0, stream>>>(nmask, vmask, I_FLAG, I_MASK, F_VAL);

  // --- beat encoder -> e, em ---
  encoder_k<<<CBN, 256, 0, stream>>>(beats, rr, c1w, c1b, c2w, c2b, fcw, fcb, mtok,
                                     I_MASK, F_VAL, F_E, F_EM);

  // --- target branch: temporal(e) -> out[0:1M] (f32) ---
  run_temporal(F_E, F_X, out,
      qkv_w, qkv_b, out_w, out_b, ln1g, ln1b, w1, b1, w2, b2, ln2g, ln2b,
      F_QKV, F_H, F_O, F_T, stream);

  // --- masked branch: temporal(em) -> F_X (f32) ---
  run_temporal(F_EM, F_X, F_X,
      qkv_w, qkv_b, out_w, out_b, ln1g, ln1b, w1, b1, w2, b2, ln2g, ln2b,
      F_QKV, F_H, F_O, F_T, stream);

  // --- graph build (per batch): sim_b = x_b @ x_b^T, topk(5) + band ---
  for (int b = 0; b < CB; ++b) {
    gemm_k<true, false, false><<<dim3(16, 16, 1), 256, 0, stream>>>(
        F_X + (long)b * 262144, 256, 0, 0, F_X + (long)b * 262144, 256, 0, 0,
        F_SIM, 1024, 0, 0, nullptr, 1.f, 256, 1);
    topk_k<<<CN, 256, 0, stream>>>(F_SIM, b, I_NBR, F_DEG);
  }

  // --- GNN layers (sparse aggregate + 2 GEMMs each) ---
  float* cur = F_X; float* oth = F_G2;
  for (int l = 0; l < CGL; ++l) {
    agg_k<<<CBN, 256, 0, stream>>>(cur, I_NBR, F_DEG, F_AGG);
    gemm_k<true, false, false><<<dim3(4, 64, 1), 256, 0, stream>>>(
        cur, 256, 0, 0, gsw + (long)l * 65536, 256, 0, 0,
        oth, 256, 0, 0, gsb + l * 256, 1.f, 256, 1);
    gemm_k<true, false, true><<<dim3(4, 64, 1), 256, 0, stream>>>(
        F_AGG, 256, 0, 0, gnw + (long)l * 65536, 256, 0, 0,
        oth, 256, 0, 0, gnb + l * 256, 1.f, 256, 1);
    float* t2 = cur; cur = oth; oth = t2;
  }

  // --- decoder: recon = x @ dec_w.T + dec_b -> out[1M:2M] (f32) ---
  gemm_k<true, false, false><<<dim3(4, 64, 1), 256, 0, stream>>>(
      cur, 256, 0, 0, dcw, 256, 0, 0, out + M1, 256, 0, 0, dcb, 1.f, 256, 1);
}